// Round 6
// baseline (224.443 us; speedup 1.0000x reference)
//
#include <hip/hip_runtime.h>

#define BTOT 1048576
#define D 17
#define H 8
#define OUT 6
#define E 4
#define G1 64
#define G2 32

typedef short bf8 __attribute__((ext_vector_type(8)));          // 8 bf16 (4 VGPR)
typedef float f4 __attribute__((ext_vector_type(4), aligned(16)));
typedef float f4u __attribute__((ext_vector_type(4), aligned(4)));
typedef float f2u __attribute__((ext_vector_type(2), aligned(4)));
typedef unsigned int u4 __attribute__((ext_vector_type(4)));

#define MFMA16 __builtin_amdgcn_mfma_f32_16x16x32_bf16

__device__ __forceinline__ unsigned int fbits(float x){ union{float f; unsigned int u;} a; a.f = x; return a.u; }
__device__ __forceinline__ float bitsf(unsigned int u){ union{unsigned int u; float f;} a; a.u = u; return a.f; }
__device__ __forceinline__ unsigned short bf_rne(float x){ unsigned int u = fbits(x); u += 0x7FFFu + ((u>>16)&1u); return (unsigned short)(u>>16); }

// 3-way split of an fp32 pair into packed bf16 levels: trunc / trunc / RNE.
__device__ __forceinline__ void split2(float a, float b,
                                       unsigned int& q1, unsigned int& q2, unsigned int& q3){
    unsigned int ua = fbits(a), ub = fbits(b);
    unsigned int a1 = ua & 0xFFFF0000u, b1 = ub & 0xFFFF0000u;
    float ra = a - bitsf(a1), rb = b - bitsf(b1);
    unsigned int a2 = fbits(ra) & 0xFFFF0000u, b2 = fbits(rb) & 0xFFFF0000u;
    float ra2 = ra - bitsf(a2), rb2 = rb - bitsf(b2);
    unsigned int a3 = fbits(ra2); a3 += 0x7FFFu + ((a3>>16)&1u);
    unsigned int b3 = fbits(rb2); b3 += 0x7FFFu + ((b3>>16)&1u);
    q1 = b1 | (a1 >> 16);
    q2 = b2 | (a2 >> 16);
    q3 = (b3 & 0xFFFF0000u) | (a3 >> 16);
}

__device__ __forceinline__ void split8(f4 lo, f4 hi, bf8& A1, bf8& A2, bf8& A3){
    unsigned int p1[4], p2[4], p3[4];
    split2(lo.x, lo.y, p1[0], p2[0], p3[0]);
    split2(lo.z, lo.w, p1[1], p2[1], p3[1]);
    split2(hi.x, hi.y, p1[2], p2[2], p3[2]);
    split2(hi.z, hi.w, p1[3], p2[3], p3[3]);
    union { u4 u; bf8 s; } r1, r2, r3;
    r1.u = (u4){p1[0], p1[1], p1[2], p1[3]};
    r2.u = (u4){p2[0], p2[1], p2[2], p2[3]};
    r3.u = (u4){p3[0], p3[1], p3[2], p3[3]};
    A1 = r1.s; A2 = r2.s; A3 = r3.s;
}

__device__ __forceinline__ unsigned short split_level(float w, int l){
    unsigned int u1 = fbits(w) & 0xFFFF0000u;
    if (l == 0) return (unsigned short)(u1 >> 16);
    float r = w - bitsf(u1);
    unsigned int u2 = fbits(r) & 0xFFFF0000u;
    if (l == 1) return (unsigned short)(u2 >> 16);
    float r2 = r - bitsf(u2);
    return bf_rne(r2);
}

// ---- Pre-kernel: MFMA B-operand layouts in workspace (bf16, [n][k] k-contig) ----
// ws ushort offsets: B1L 0 (3*64*32) | B2L 6144 (3*32*64) | Be1 12288 (32*32)
//                    Be2 13312 (32*32, block-diag) | Be3 14336 (16*32, expert-stacked)
__global__ void hybrid_pre(const float* __restrict__ eW1, const float* __restrict__ eW2,
                           const float* __restrict__ eW3, const float* __restrict__ gW1,
                           const float* __restrict__ gW2, unsigned short* __restrict__ wsB)
{
    const int t = threadIdx.x;
    for (int i = t; i < 3*64*32; i += 256) {                 // B1L[l][n][k]
        int k = i & 31, n = (i >> 5) & 63, l = i >> 11;
        float w = (k < D) ? gW1[k*G1 + n] : 0.f;
        wsB[i] = split_level(w, l);
    }
    for (int i = t; i < 3*32*64; i += 256) {                 // B2L[l][n][k]
        int k = i & 63, n = (i >> 6) & 31, l = i >> 11;
        float w = gW2[k*G2 + n];
        wsB[6144 + i] = split_level(w, l);
    }
    for (int i = t; i < 1024; i += 256) {                    // Be1[n][k]: n={e,h}
        int k = i & 31, n = i >> 5, e = n >> 3, h = n & 7;
        float w = (k < D) ? eW1[(e*D + k)*H + h] : 0.f;
        wsB[12288 + i] = bf_rne(w);
    }
    for (int i = t; i < 1024; i += 256) {                    // Be2[n][k] block-diag
        int k = i & 31, n = i >> 5, e = n >> 3, j = n & 7, kk = k - e*8;
        float w = (kk >= 0 && kk < 8) ? eW2[(e*H + kk)*H + j] : 0.f;
        wsB[13312 + i] = bf_rne(w);
    }
    for (int i = t; i < 512; i += 256) {                     // Be3[n][k] expert-stacked
        int k = i & 31, n = i >> 5, e = k >> 3, kk = k & 7;
        float w = (n < OUT) ? eW3[(e*H + kk)*OUT + n] : 0.f;
        wsB[14336 + i] = bf_rne(w);
    }
}

// ---- Main: 4 waves/block, each wave owns 64 samples, 13312B private LDS slice.
// ---- 52KB LDS/block -> 3 blocks/CU (vs 2 at round 5). No __syncthreads. ----
__global__ __launch_bounds__(256, 3) void hybrid_main(
    const float* __restrict__ x,
    const float* __restrict__ eb1, const float* __restrict__ eb2, const float* __restrict__ eb3,
    const float* __restrict__ gb1, const float* __restrict__ gb2,
    const float* __restrict__ gW3, const float* __restrict__ gb3,
    const unsigned short* __restrict__ wsB,
    float* __restrict__ out)
{
    __shared__ char lds_all[4 * 13312];
    const int tid = threadIdx.x;
    const int wave = tid >> 6, lane = tid & 63;
    const int q = lane >> 4, c = lane & 15;
    char* slice = lds_all + wave * 13312;
    // Phase-ordered aliased regions (within-wave in-order DS pipe; wave_barrier
    // is a compiler fence only — pattern validated by round 5):
    float* sh1t = (float*)slice;                            // [16][67] f32 (per-mt h1)
    float* sh2  = (float*)(slice + 4352);                   // [64][33] f32 (gating)
    int*   ssel = (int*)(slice + 12800);                    // [64] (persists)
    unsigned short* sAe2 = (unsigned short*)slice;          // [64][40] bf16 (experts)
    unsigned short* sAe3 = (unsigned short*)(slice + 5120); // [64][40] bf16
    float* spred = (float*)(slice + 10240);                 // [64][8] f32

    const long long samp0 = (long long)blockIdx.x * 256 + wave * 64;

    // ---- Persistent gating B-frags + biases ----
    bf8 B1f[4][3];
    #pragma unroll
    for (int nt = 0; nt < 4; ++nt)
        #pragma unroll
        for (int l = 0; l < 3; ++l)
            B1f[nt][l] = *(const bf8*)(wsB + ((l*64 + nt*16 + c)*32 + q*8));
    bf8 B2f[2][2][3];
    #pragma unroll
    for (int nt = 0; nt < 2; ++nt)
        #pragma unroll
        for (int ks = 0; ks < 2; ++ks)
            #pragma unroll
            for (int l = 0; l < 3; ++l)
                B2f[nt][ks][l] = *(const bf8*)(wsB + 6144 + ((l*32 + nt*16 + c)*64 + ks*32 + q*8));
    float bias1[4], bias2[2];
    #pragma unroll
    for (int nt = 0; nt < 4; ++nt) bias1[nt] = gb1[nt*16 + c];
    #pragma unroll
    for (int nt = 0; nt < 2; ++nt) bias2[nt] = gb2[nt*16 + c];

    bf8 A1[4];                               // level-1 x frags (reused by experts)

    // ---- Gating, tiled by mt: L1 -> sh1t -> L2 -> sh2 ----
    #pragma unroll
    for (int mt = 0; mt < 4; ++mt) {
        // A-frag direct from global: row m = mt*16+c, k = q*8..q*8+7 (k<17)
        const float* rp = x + (samp0 + mt*16 + c) * D;
        f4 lo = {0.f,0.f,0.f,0.f}, hi = {0.f,0.f,0.f,0.f};
        if (q < 2) {
            f4u a = *(const f4u*)(rp + q*8), b = *(const f4u*)(rp + q*8 + 4);
            lo = (f4){a.x,a.y,a.z,a.w}; hi = (f4){b.x,b.y,b.z,b.w};
        } else if (q == 2) {
            lo.x = rp[16];
        }
        bf8 A2, A3;
        split8(lo, hi, A1[mt], A2, A3);

        // L1: 4 nt tiles, 7-product split, epilogue -> sh1t (stride 67: <=2-way)
        #pragma unroll
        for (int nt = 0; nt < 4; ++nt) {
            f4 am = {0.f,0.f,0.f,0.f}, ac = {0.f,0.f,0.f,0.f};
            am = MFMA16(A1[mt], B1f[nt][0], am, 0,0,0);
            ac = MFMA16(A1[mt], B1f[nt][1], ac, 0,0,0);
            ac = MFMA16(A2,     B1f[nt][0], ac, 0,0,0);
            ac = MFMA16(A1[mt], B1f[nt][2], ac, 0,0,0);
            ac = MFMA16(A2,     B1f[nt][1], ac, 0,0,0);
            ac = MFMA16(A3,     B1f[nt][0], ac, 0,0,0);
            ac = MFMA16(A3,     B1f[nt][1], ac, 0,0,0);
            #pragma unroll
            for (int r = 0; r < 4; ++r) {
                float h = fmaxf(am[r] + ac[r] + bias1[nt], 0.f);
                sh1t[(q*4 + r)*67 + nt*16 + c] = h;
            }
        }
        __builtin_amdgcn_wave_barrier();

        // L2 for this mt: C-splits from sh1t, accumulate 2 nt tiles over 2 ks
        f4 am2[2], ac2[2];
        am2[0] = am2[1] = ac2[0] = ac2[1] = (f4){0.f,0.f,0.f,0.f};
        #pragma unroll
        for (int ks = 0; ks < 2; ++ks) {
            const float* src = sh1t + c*67 + ks*32 + q*8;
            f4 lo2 = {src[0], src[1], src[2], src[3]};
            f4 hi2 = {src[4], src[5], src[6], src[7]};
            bf8 C1, C2, C3;
            split8(lo2, hi2, C1, C2, C3);
            #pragma unroll
            for (int nt = 0; nt < 2; ++nt) {
                am2[nt] = MFMA16(C1, B2f[nt][ks][0], am2[nt], 0,0,0);
                ac2[nt] = MFMA16(C1, B2f[nt][ks][1], ac2[nt], 0,0,0);
                ac2[nt] = MFMA16(C2, B2f[nt][ks][0], ac2[nt], 0,0,0);
                ac2[nt] = MFMA16(C1, B2f[nt][ks][2], ac2[nt], 0,0,0);
                ac2[nt] = MFMA16(C2, B2f[nt][ks][1], ac2[nt], 0,0,0);
                ac2[nt] = MFMA16(C3, B2f[nt][ks][0], ac2[nt], 0,0,0);
                ac2[nt] = MFMA16(C3, B2f[nt][ks][1], ac2[nt], 0,0,0);
            }
        }
        #pragma unroll
        for (int nt = 0; nt < 2; ++nt)
            #pragma unroll
            for (int r = 0; r < 4; ++r) {
                float h = fmaxf(am2[nt][r] + ac2[nt][r] + bias2[nt], 0.f);
                sh2[(mt*16 + q*4 + r)*33 + nt*16 + c] = h;
            }
        __builtin_amdgcn_wave_barrier();
    }

    // ---- L3 (per-thread fp32): logits, argmax, store logits. Stride-33 reads
    // ---- are conflict-free (bank = lane+k). Same accumulation order as R5. ----
    {
        const float* hr = sh2 + lane*33;
        float lg[E];
        #pragma unroll
        for (int e = 0; e < E; ++e) lg[e] = gb3[e];
        #pragma unroll
        for (int k = 0; k < G2; ++k) {
            float h = hr[k];
            #pragma unroll
            for (int e = 0; e < E; ++e)
                lg[e] = __builtin_fmaf(h, gW3[k*E + e], lg[e]);
        }
        int sel = 0; float best = lg[0];
        #pragma unroll
        for (int e = 1; e < E; ++e) if (lg[e] > best) { best = lg[e]; sel = e; }
        ssel[lane] = sel;
        float* lo = out + (long long)BTOT * OUT + (samp0 + lane) * E;
        *(f4*)lo = (f4){lg[0], lg[1], lg[2], lg[3]};
    }
    __builtin_amdgcn_wave_barrier();

    // ---- Experts (bf16 MFMA; mask at t2; stacked W3 emits selected expert) ----
    bf8 Be1f[2], Be2f[2], Be3f;
    #pragma unroll
    for (int nt = 0; nt < 2; ++nt) {
        Be1f[nt] = *(const bf8*)(wsB + 12288 + (nt*16 + c)*32 + q*8);
        Be2f[nt] = *(const bf8*)(wsB + 13312 + (nt*16 + c)*32 + q*8);
    }
    Be3f = *(const bf8*)(wsB + 14336 + c*32 + q*8);
    float be1v[2], be2v[2];
    #pragma unroll
    for (int nt = 0; nt < 2; ++nt) { be1v[nt] = eb1[nt*16 + c]; be2v[nt] = eb2[nt*16 + c]; }

    #pragma unroll
    for (int mt = 0; mt < 4; ++mt) {                       // eL1: A1 -> t1 (bf16)
        #pragma unroll
        for (int nt = 0; nt < 2; ++nt) {
            f4 acc = {0.f,0.f,0.f,0.f};
            acc = MFMA16(A1[mt], Be1f[nt], acc, 0,0,0);
            #pragma unroll
            for (int r = 0; r < 4; ++r) {
                float t = fmaxf(acc[r] + be1v[nt], 0.f);
                sAe2[(mt*16 + q*4 + r)*40 + nt*16 + c] = (unsigned short)(fbits(t) >> 16);
            }
        }
    }
    __builtin_amdgcn_wave_barrier();

    #pragma unroll
    for (int mt = 0; mt < 4; ++mt) {                       // eL2 (block-diag) -> masked t2
        bf8 Af = *(const bf8*)(sAe2 + (mt*16 + c)*40 + q*8);
        f4 acc[2];
        #pragma unroll
        for (int nt = 0; nt < 2; ++nt) {
            acc[nt] = (f4){0.f,0.f,0.f,0.f};
            acc[nt] = MFMA16(Af, Be2f[nt], acc[nt], 0,0,0);
        }
        #pragma unroll
        for (int r = 0; r < 4; ++r) {
            int row = mt*16 + q*4 + r;
            int se = ssel[row];
            #pragma unroll
            for (int nt = 0; nt < 2; ++nt) {
                int ecol = nt*2 + (c>>3);
                float t = (se == ecol) ? fmaxf(acc[nt][r] + be2v[nt], 0.f) : 0.f;
                sAe3[row*40 + nt*16 + c] = (unsigned short)(fbits(t) >> 16);
            }
        }
    }
    __builtin_amdgcn_wave_barrier();

    #pragma unroll
    for (int mt = 0; mt < 4; ++mt) {                       // eL3 (stacked) -> pred
        bf8 Af = *(const bf8*)(sAe3 + (mt*16 + c)*40 + q*8);
        f4 acc = {0.f,0.f,0.f,0.f};
        acc = MFMA16(Af, Be3f, acc, 0,0,0);
        #pragma unroll
        for (int r = 0; r < 4; ++r) {
            int row = mt*16 + q*4 + r;
            int se = ssel[row];
            if (c < OUT) spred[row*8 + c] = acc[r] + eb3[se*OUT + c];
        }
    }
    __builtin_amdgcn_wave_barrier();

    // ---- pred store (thread-major, vectorized) ----
    {
        const float* pr = spred + lane*8;
        f4 p0 = *(const f4*)pr;
        float p4 = pr[4], p5 = pr[5];
        float* po = out + (samp0 + lane) * OUT;
        *(f4u*)po = p0;
        *(f2u*)(po + 4) = (f2u){p4, p5};
    }
}

extern "C" void kernel_launch(void* const* d_in, const int* in_sizes, int n_in,
                              void* d_out, int out_size, void* d_ws, size_t ws_size,
                              hipStream_t stream) {
    const float* x   = (const float*)d_in[0];
    const float* eW1 = (const float*)d_in[1];
    const float* eb1 = (const float*)d_in[2];
    const float* eW2 = (const float*)d_in[3];
    const float* eb2 = (const float*)d_in[4];
    const float* eW3 = (const float*)d_in[5];
    const float* eb3 = (const float*)d_in[6];
    const float* gW1 = (const float*)d_in[7];
    const float* gb1 = (const float*)d_in[8];
    const float* gW2 = (const float*)d_in[9];
    const float* gb2 = (const float*)d_in[10];
    const float* gW3 = (const float*)d_in[11];
    const float* gb3 = (const float*)d_in[12];
    float* out = (float*)d_out;
    unsigned short* wsB = (unsigned short*)d_ws;

    hipLaunchKernelGGL(hybrid_pre, dim3(1), dim3(256), 0, stream,
                       eW1, eW2, eW3, gW1, gW2, wsB);
    hipLaunchKernelGGL(hybrid_main, dim3(BTOT / 256), dim3(256), 0, stream,
                       x, eb1, eb2, eb3, gb1, gb2, gW3, gb3, wsB, out);
}